// Round 3
// baseline (324.896 us; speedup 1.0000x reference)
//
#include <hip/hip_runtime.h>
#include <math.h>

#define B_ 64
#define IC 2048
#define OC 32
#define OD 16
#define ID 8

#define GLOAD_LDS16(gp, lp)                                                       \
  __builtin_amdgcn_global_load_lds((const __attribute__((address_space(1))) void*)(gp), \
                                   (__attribute__((address_space(3))) void*)(lp), \
                                   16, 0, 0)

__device__ __forceinline__ float dot8(const float4 w0, const float4 w1,
                                      const float4 xa, const float4 xb) {
  return w0.x*xa.x + w0.y*xa.y + w0.z*xa.z + w0.w*xa.w
       + w1.x*xb.x + w1.y*xb.y + w1.z*xb.z + w1.w*xb.w;
}

// ---------------------------------------------------------------------------
// Fused routing kernel (recompute u_hat; b-logit update + unnormalized
// exp-weighted s accumulation; Z applied later in reduceSquash).
// MODE 0: iter1 uniform c. MODE 1: iter2 (b_old=0, writes bl). MODE 2: iter3.
//
// grid = 4*NCH: bid&3 = bq (b-quarter, 16 b's), bid>>2 = ch (i-chunk of CI).
// 256 threads: slot=t&127 -> o=slot>>2, dq=slot&3; bg=t>>7 -> 8 b's/thread.
//
// W[i] (16KB) staged per-i into LDS via global_load_lds, double-buffered,
// with XOR-swizzled SOURCE so the ds_read_b128 of 8 contiguous float4s per
// thread is bank-conflict-minimal:
//   LDS f4 slot p holds W f4  src(p) = (p&~7) | ((p&7) ^ ((p>>3)&7))
//   thread reads wr[r] at LDS f4  slot*8 + (r ^ (slot&7))  == W f4 slot*8+r.
// ---------------------------------------------------------------------------
template<int MODE, int NCH>
__global__ __launch_bounds__(256, 3) void fusedK(
    const float* __restrict__ x, const float* __restrict__ W,
    const float* __restrict__ v, const float* __restrict__ blin,
    float* __restrict__ blout, float* __restrict__ part,
    float* __restrict__ zpart)
{
  constexpr int CI = IC / NCH;
  const int t    = threadIdx.x;
  const int bq   = blockIdx.x & 3;
  const int ch   = blockIdx.x >> 2;
  const int slot = t & 127;
  const int bg   = t >> 7;
  const int o    = slot >> 2;
  const int dq   = slot & 3;
  const int lane = t & 63;
  const int w    = t >> 6;
  const int i0   = ch * CI;
  const int bqb  = bq * 16;            // block's first b
  const int s7   = slot & 7;
  const int sbase = slot * 8;          // f4 base of this thread's W slice

  __shared__ float Wbuf[2][4096];                         // 2 x 16 KB
  __shared__ float xbuf[2][128];                          // 2 x 512 B
  __shared__ float blbuf[(MODE == 2) ? 2 : 1][(MODE == 2) ? 512 : 4];

  const float4* Wg  = (const float4*)W;
  const float4* xg  = (const float4*)x;
  const float4* blg = (const float4*)blin;

  float4 accv[8];
  float  zacc[8];
  float4 vreg[8];
#pragma unroll
  for (int bb = 0; bb < 8; ++bb) { accv[bb] = make_float4(0,0,0,0); zacc[bb] = 0.f; }

  if constexpr (MODE != 0) {
#pragma unroll
    for (int bb = 0; bb < 8; ++bb) {
      const int b = bqb + bg * 8 + bb;
      vreg[bb] = *(const float4*)(v + ((size_t)b * 32 + o) * 16 + dq * 4);
    }
  }

  auto stage = [&](int i, int nb) {
    // W[i]: 4 gload rounds per wave, swizzled source
    const float4* Wi = Wg + (size_t)i * 1024;
#pragma unroll
    for (int k = 0; k < 4; ++k) {
      const int p   = w * 256 + k * 64 + lane;
      const int src = (p & ~7) | ((p & 7) ^ ((p >> 3) & 7));
      GLOAD_LDS16(Wi + src, &Wbuf[nb][(w * 256 + k * 64) * 4]);
    }
    // x[bqb..bqb+16, i, 0..8): 32 f4, wave 0 lanes 0..31, linear dest
    if (t < 32) {
      GLOAD_LDS16(xg + (size_t)(bqb + (t >> 1)) * 4096 + i * 2 + (t & 1),
                  &xbuf[nb][0]);
    }
    // bl[i, bqb..bqb+16, 0..32): 128 f4, waves 0-1, linear dest
    if constexpr (MODE == 2) {
      if (t < 128) {
        GLOAD_LDS16(blg + (size_t)i * 512 + bq * 128 + t,
                    &blbuf[nb][(t >> 6) * 256]);
      }
    }
  };

  stage(i0, 0);
  __syncthreads();

  for (int ii = 0; ii < CI; ++ii) {
    const int cur = ii & 1;
    const int i   = i0 + ii;
    if (ii + 1 < CI) stage(i + 1, cur ^ 1);

    // W fragment from LDS (swizzled addresses; wr[r] == W f4 slot*8+r)
    const float* Wb = &Wbuf[cur][0];
    float4 wr[8];
#pragma unroll
    for (int r = 0; r < 8; ++r)
      wr[r] = *(const float4*)&Wb[(sbase + (r ^ s7)) * 4];

#pragma unroll
    for (int bb = 0; bb < 8; ++bb) {
      const int bl_loc = bg * 8 + bb;                    // b-local in [0,16)
      const float4 xa = *(const float4*)&xbuf[cur][bl_loc * 8];
      const float4 xc = *(const float4*)&xbuf[cur][bl_loc * 8 + 4];
      float4 u;
      u.x = dot8(wr[0], wr[1], xa, xc);
      u.y = dot8(wr[2], wr[3], xa, xc);
      u.z = dot8(wr[4], wr[5], xa, xc);
      u.w = dot8(wr[6], wr[7], xa, xc);
      if constexpr (MODE == 0) {
        accv[bb].x += u.x; accv[bb].y += u.y;
        accv[bb].z += u.z; accv[bb].w += u.w;
      } else {
        const float4 vv = vreg[bb];
        float pd = u.x * vv.x + u.y * vv.y + u.z * vv.z + u.w * vv.w;
        pd += __shfl_xor(pd, 1);             // reduce over dq (lane bits 0-1)
        pd += __shfl_xor(pd, 2);
        float bnew = pd;
        if constexpr (MODE == 2) bnew += blbuf[cur][bl_loc * 32 + o];
        if constexpr (MODE == 1) {
          if (dq == 0)
            blout[(size_t)i * 2048 + (size_t)(bqb + bl_loc) * 32 + o] = bnew;
        }
        const float p = __expf(bnew);
        accv[bb].x = fmaf(p, u.x, accv[bb].x);
        accv[bb].y = fmaf(p, u.y, accv[bb].y);
        accv[bb].z = fmaf(p, u.z, accv[bb].z);
        accv[bb].w = fmaf(p, u.w, accv[bb].w);
        zacc[bb] += p;
      }
    }
    __syncthreads();
  }

  // epilogue: part[ch][b][o][d] as f4 at dq; zpart[ch][b*32+o]
  float4* part4 = (float4*)part;
#pragma unroll
  for (int bb = 0; bb < 8; ++bb) {
    const int b = bqb + bg * 8 + bb;
    part4[((size_t)ch * 64 + b) * 128 + o * 4 + dq] = accv[bb];
    if constexpr (MODE != 0) {
      if (dq == 0) zpart[(size_t)ch * 2048 + b * 32 + o] = zacc[bb];
    }
  }
}

// ---------------------------------------------------------------------------
// Reduce s partials over chunks, normalize by Z (or uniform scale), squash.
// grid 128 x 256; one thread per (b,o,d); g = b*512 + o*16 + d.
// ---------------------------------------------------------------------------
template<bool WITH_Z, int NCH>
__global__ __launch_bounds__(256) void reduceSquash(
    const float* __restrict__ part, const float* __restrict__ rz,
    float* __restrict__ vout, float scale)
{
  const int g = blockIdx.x * 256 + threadIdx.x;
  float s = 0.f;
#pragma unroll 8
  for (int ch = 0; ch < NCH; ++ch) s += part[(size_t)ch * 32768 + g];
  if constexpr (WITH_Z) s *= rz[g >> 4];
  else                  s *= scale;

  float sq = s * s;
#pragma unroll
  for (int k = 1; k < 16; k <<= 1) sq += __shfl_xor(sq, k);   // sum over d
  const float f = (sq / (1.f + sq)) * rsqrtf(sq + 1e-9f);
  vout[g] = s * f;
}

// ---------------------------------------------------------------------------
// Z reduction: rz[b*32+o] = 1 / sum_ch zpart[ch][...]. grid 8 x 256.
// ---------------------------------------------------------------------------
template<int NCH>
__global__ __launch_bounds__(256) void zredK(
    const float* __restrict__ zpart, float* __restrict__ rz)
{
  const int j = blockIdx.x * 256 + threadIdx.x;
  float zs = 0.f;
#pragma unroll 8
  for (int ch = 0; ch < NCH; ++ch) zs += zpart[(size_t)ch * 2048 + j];
  rz[j] = 1.f / zs;
}

// ---------------------------------------------------------------------------
extern "C" void kernel_launch(void* const* d_in, const int* in_sizes, int n_in,
                              void* d_out, int out_size, void* d_ws, size_t ws_size,
                              hipStream_t stream) {
  (void)in_sizes; (void)n_in; (void)out_size;
  const float* x = (const float*)d_in[0];
  const float* W = (const float*)d_in[1];
  float* out = (float*)d_out;
  float* ws  = (float*)d_ws;

  auto run = [&](auto tag) {
    constexpr int NCH = decltype(tag)::value;
    float* bl    = ws;                                 // [2048][64][32]
    float* part  = bl + (size_t)IC * B_ * OC;          // [NCH][64][32][16]
    float* zpart = part + (size_t)NCH * 32768;         // [NCH][2048]
    float* rz    = zpart + (size_t)NCH * 2048;         // [2048]
    float* v     = rz + 2048;                          // [64][32][16]

    const dim3 gF(4 * NCH), b256(256);
    // iter 1: uniform c = 1/2048
    fusedK<0, NCH><<<gF, b256, 0, stream>>>(x, W, nullptr, nullptr, nullptr, part, nullptr);
    reduceSquash<false, NCH><<<dim3(128), b256, 0, stream>>>(part, nullptr, v, 1.f / 2048.f);
    // iter 2: b1 = u.v1 (written to bl), s2 = sum exp(b1) u / Z
    fusedK<1, NCH><<<gF, b256, 0, stream>>>(x, W, v, nullptr, bl, part, zpart);
    zredK<NCH><<<dim3(8), b256, 0, stream>>>(zpart, rz);
    reduceSquash<true, NCH><<<dim3(128), b256, 0, stream>>>(part, rz, v, 0.f);
    // iter 3: b2 = b1 + u.v2, s3, final v -> out
    fusedK<2, NCH><<<gF, b256, 0, stream>>>(x, W, v, bl, nullptr, part, zpart);
    zredK<NCH><<<dim3(8), b256, 0, stream>>>(zpart, rz);
    reduceSquash<true, NCH><<<dim3(128), b256, 0, stream>>>(part, rz, out, 0.f);
  };

  const size_t need256 =
      ((size_t)IC * B_ * OC + 256ul * 32768 + 256ul * 2048 + 2048 + 32768) * 4;
  if (ws_size >= need256) run(std::integral_constant<int, 256>{});
  else                    run(std::integral_constant<int, 64>{});
}

// Round 4
// 183.185 us; speedup vs baseline: 1.7736x; 1.7736x over previous
//
#include <hip/hip_runtime.h>
#include <math.h>

#define B_ 64
#define IC 2048
#define OC 32
#define OD 16
#define ID 8

#define GLOAD_LDS16(gp, lp)                                                       \
  __builtin_amdgcn_global_load_lds((const __attribute__((address_space(1))) void*)(gp), \
                                   (__attribute__((address_space(3))) void*)(lp), \
                                   16, 0, 0)

__device__ __forceinline__ float dot8(const float4 w0, const float4 w1,
                                      const float4 xa, const float4 xb) {
  return w0.x*xa.x + w0.y*xa.y + w0.z*xa.z + w0.w*xa.w
       + w1.x*xb.x + w1.y*xb.y + w1.z*xb.z + w1.w*xb.w;
}

// ---------------------------------------------------------------------------
// Fused routing kernel (recompute u_hat; b-logit update + unnormalized
// exp-weighted s accumulation; Z applied later in reduceSquash).
// MODE 0: iter1 uniform c. MODE 1: iter2 (b_old=0, writes bl). MODE 2: iter3.
//
// grid = 4*NCH, remapped for XCD locality: xcd = bid&7, q = bid>>3;
//   ch = (q>>2)*8 + xcd  (i-chunk of CI),  bq = q&3  (b-quarter, 16 b's).
// The 4 bq-blocks of one ch run concurrently on ONE XCD -> its L2 serves the
// 128KB W window once instead of 4 HBM fetches.
//
// 256 threads: slot=t&127 -> o=slot>>2, dq=slot&3; bg=t>>7 -> 8 b's/thread.
//
// W[i] (16KB) staged per-i into LDS via global_load_lds, double-buffered,
// with XOR-swizzled SOURCE so the per-thread ds_read_b128 of 8 contiguous
// float4s is bank-conflict-free (8-phase minimum):
//   LDS f4 slot p holds W f4  src(p) = (p&~7) | ((p&7) ^ ((p>>3)&7))
//   thread reads wr[r] at LDS f4 slot*8 + (r ^ (slot&7))  == W f4 slot*8+r.
// ---------------------------------------------------------------------------
template<int MODE, int NCH>
__global__ __launch_bounds__(256) void fusedK(
    const float* __restrict__ x, const float* __restrict__ W,
    const float* __restrict__ v, const float* __restrict__ blin,
    float* __restrict__ blout, float* __restrict__ part,
    float* __restrict__ zpart)
{
  constexpr int CI = IC / NCH;
  const int t    = threadIdx.x;
  const int xcd  = blockIdx.x & 7;
  const int q    = blockIdx.x >> 3;
  const int ch   = (q >> 2) * 8 + xcd;
  const int bq   = q & 3;
  const int slot = t & 127;
  const int bg   = t >> 7;
  const int o    = slot >> 2;
  const int dq   = slot & 3;
  const int lane = t & 63;
  const int w    = t >> 6;
  const int i0   = ch * CI;
  const int bqb  = bq * 16;            // block's first b
  const int s7   = slot & 7;
  const int sbase = slot * 8;          // f4 base of this thread's W slice

  __shared__ float Wbuf[2][4096];                         // 2 x 16 KB
  __shared__ float xbuf[2][128];                          // 2 x 512 B
  __shared__ float blbuf[(MODE == 2) ? 2 : 1][(MODE == 2) ? 512 : 4];

  const float4* Wg  = (const float4*)W;
  const float4* xg  = (const float4*)x;
  const float4* blg = (const float4*)blin;

  float4 accv[8];
  float  zacc[8];
  float4 vreg[8];
#pragma unroll
  for (int bb = 0; bb < 8; ++bb) { accv[bb] = make_float4(0,0,0,0); zacc[bb] = 0.f; }

  if constexpr (MODE != 0) {
#pragma unroll
    for (int bb = 0; bb < 8; ++bb) {
      const int b = bqb + bg * 8 + bb;
      vreg[bb] = *(const float4*)(v + ((size_t)b * 32 + o) * 16 + dq * 4);
    }
  }

  auto stage = [&](int i, int nb) {
    // W[i]: 4 gload rounds per wave, swizzled source, linear LDS dest
    const float4* Wi = Wg + (size_t)i * 1024;
#pragma unroll
    for (int k = 0; k < 4; ++k) {
      const int p   = w * 256 + k * 64 + lane;
      const int src = (p & ~7) | ((p & 7) ^ ((p >> 3) & 7));
      GLOAD_LDS16(Wi + src, &Wbuf[nb][(w * 256 + k * 64) * 4]);
    }
    // x[bqb..bqb+16, i, 0..8): 32 f4, wave 0 lanes 0..31, linear dest
    if (t < 32) {
      GLOAD_LDS16(xg + (size_t)(bqb + (t >> 1)) * 4096 + i * 2 + (t & 1),
                  &xbuf[nb][0]);
    }
    // bl[i, bqb..bqb+16, 0..32): 128 f4, waves 0-1, linear dest
    if constexpr (MODE == 2) {
      if (t < 128) {
        GLOAD_LDS16(blg + (size_t)i * 512 + bq * 128 + t,
                    &blbuf[nb][(t >> 6) * 256]);
      }
    }
  };

  stage(i0, 0);
  __syncthreads();

  for (int ii = 0; ii < CI; ++ii) {
    const int cur = ii & 1;
    const int i   = i0 + ii;
    if (ii + 1 < CI) stage(i + 1, cur ^ 1);

    // W fragment from LDS (swizzled addresses; wr[r] == W f4 slot*8+r)
    const float* Wb = &Wbuf[cur][0];
    float4 wr[8];
#pragma unroll
    for (int r = 0; r < 8; ++r)
      wr[r] = *(const float4*)&Wb[(sbase + (r ^ s7)) * 4];

#pragma unroll
    for (int bb = 0; bb < 8; ++bb) {
      const int bl_loc = bg * 8 + bb;                    // b-local in [0,16)
      const float4 xa = *(const float4*)&xbuf[cur][bl_loc * 8];
      const float4 xc = *(const float4*)&xbuf[cur][bl_loc * 8 + 4];
      float4 u;
      u.x = dot8(wr[0], wr[1], xa, xc);
      u.y = dot8(wr[2], wr[3], xa, xc);
      u.z = dot8(wr[4], wr[5], xa, xc);
      u.w = dot8(wr[6], wr[7], xa, xc);
      if constexpr (MODE == 0) {
        accv[bb].x += u.x; accv[bb].y += u.y;
        accv[bb].z += u.z; accv[bb].w += u.w;
      } else {
        const float4 vv = vreg[bb];
        float pd = u.x * vv.x + u.y * vv.y + u.z * vv.z + u.w * vv.w;
        pd += __shfl_xor(pd, 1);             // reduce over dq (lane bits 0-1)
        pd += __shfl_xor(pd, 2);
        float bnew = pd;
        if constexpr (MODE == 2) bnew += blbuf[cur][bl_loc * 32 + o];
        if constexpr (MODE == 1) {
          if (dq == 0)
            blout[(size_t)i * 2048 + (size_t)(bqb + bl_loc) * 32 + o] = bnew;
        }
        const float p = __expf(bnew);
        accv[bb].x = fmaf(p, u.x, accv[bb].x);
        accv[bb].y = fmaf(p, u.y, accv[bb].y);
        accv[bb].z = fmaf(p, u.z, accv[bb].z);
        accv[bb].w = fmaf(p, u.w, accv[bb].w);
        zacc[bb] += p;
      }
    }
    __syncthreads();
  }

  // epilogue: part[ch][b][o][d] as f4 at dq; zpart[ch][b*32+o]
  float4* part4 = (float4*)part;
#pragma unroll
  for (int bb = 0; bb < 8; ++bb) {
    const int b = bqb + bg * 8 + bb;
    part4[((size_t)ch * 64 + b) * 128 + o * 4 + dq] = accv[bb];
    if constexpr (MODE != 0) {
      if (dq == 0) zpart[(size_t)ch * 2048 + b * 32 + o] = zacc[bb];
    }
  }
}

// ---------------------------------------------------------------------------
// Reduce s partials over chunks, normalize by Z (or uniform scale), squash.
// grid 128 x 256; one thread per (b,o,d); g = b*512 + o*16 + d.
// ---------------------------------------------------------------------------
template<bool WITH_Z, int NCH>
__global__ __launch_bounds__(256) void reduceSquash(
    const float* __restrict__ part, const float* __restrict__ rz,
    float* __restrict__ vout, float scale)
{
  const int g = blockIdx.x * 256 + threadIdx.x;
  float s = 0.f;
#pragma unroll 8
  for (int ch = 0; ch < NCH; ++ch) s += part[(size_t)ch * 32768 + g];
  if constexpr (WITH_Z) s *= rz[g >> 4];
  else                  s *= scale;

  float sq = s * s;
#pragma unroll
  for (int k = 1; k < 16; k <<= 1) sq += __shfl_xor(sq, k);   // sum over d
  const float f = (sq / (1.f + sq)) * rsqrtf(sq + 1e-9f);
  vout[g] = s * f;
}

// ---------------------------------------------------------------------------
// Z reduction: rz[b*32+o] = 1 / sum_ch zpart[ch][...]. grid 8 x 256.
// ---------------------------------------------------------------------------
template<int NCH>
__global__ __launch_bounds__(256) void zredK(
    const float* __restrict__ zpart, float* __restrict__ rz)
{
  const int j = blockIdx.x * 256 + threadIdx.x;
  float zs = 0.f;
#pragma unroll 8
  for (int ch = 0; ch < NCH; ++ch) zs += zpart[(size_t)ch * 2048 + j];
  rz[j] = 1.f / zs;
}

// ---------------------------------------------------------------------------
extern "C" void kernel_launch(void* const* d_in, const int* in_sizes, int n_in,
                              void* d_out, int out_size, void* d_ws, size_t ws_size,
                              hipStream_t stream) {
  (void)in_sizes; (void)n_in; (void)out_size;
  const float* x = (const float*)d_in[0];
  const float* W = (const float*)d_in[1];
  float* out = (float*)d_out;
  float* ws  = (float*)d_ws;

  auto run = [&](auto tag) {
    constexpr int NCH = decltype(tag)::value;
    float* bl    = ws;                                 // [2048][64][32]
    float* part  = bl + (size_t)IC * B_ * OC;          // [NCH][64][32][16]
    float* zpart = part + (size_t)NCH * 32768;         // [NCH][2048]
    float* rz    = zpart + (size_t)NCH * 2048;         // [2048]
    float* v     = rz + 2048;                          // [64][32][16]

    const dim3 gF(4 * NCH), b256(256);
    // iter 1: uniform c = 1/2048
    fusedK<0, NCH><<<gF, b256, 0, stream>>>(x, W, nullptr, nullptr, nullptr, part, nullptr);
    reduceSquash<false, NCH><<<dim3(128), b256, 0, stream>>>(part, nullptr, v, 1.f / 2048.f);
    // iter 2: b1 = u.v1 (written to bl), s2 = sum exp(b1) u / Z
    fusedK<1, NCH><<<gF, b256, 0, stream>>>(x, W, v, nullptr, bl, part, zpart);
    zredK<NCH><<<dim3(8), b256, 0, stream>>>(zpart, rz);
    reduceSquash<true, NCH><<<dim3(128), b256, 0, stream>>>(part, rz, v, 0.f);
    // iter 3: b2 = b1 + u.v2, s3, final v -> out
    fusedK<2, NCH><<<gF, b256, 0, stream>>>(x, W, v, bl, nullptr, part, zpart);
    zredK<NCH><<<dim3(8), b256, 0, stream>>>(zpart, rz);
    reduceSquash<true, NCH><<<dim3(128), b256, 0, stream>>>(part, rz, out, 0.f);
  };

  const size_t need256 =
      ((size_t)IC * B_ * OC + 256ul * 32768 + 256ul * 2048 + 2048 + 32768) * 4;
  if (ws_size >= need256) run(std::integral_constant<int, 256>{});
  else                    run(std::integral_constant<int, 64>{});
}

// Round 5
// 182.454 us; speedup vs baseline: 1.7807x; 1.0040x over previous
//
#include <hip/hip_runtime.h>
#include <math.h>

#define B_ 64
#define IC 2048
#define OC 32
#define OD 16
#define ID 8

#define GLOAD_LDS16(gp, lp)                                                       \
  __builtin_amdgcn_global_load_lds((const __attribute__((address_space(1))) void*)(gp), \
                                   (__attribute__((address_space(3))) void*)(lp), \
                                   16, 0, 0)

__device__ __forceinline__ float dot8(const float4 w0, const float4 w1,
                                      const float4 xa, const float4 xb) {
  return w0.x*xa.x + w0.y*xa.y + w0.z*xa.z + w0.w*xa.w
       + w1.x*xb.x + w1.y*xb.y + w1.z*xb.z + w1.w*xb.w;
}

// ---------------------------------------------------------------------------
// Fused routing kernel (recompute u_hat; b-logit update + unnormalized
// exp-weighted s accumulation; Z applied later in reduceSquash).
// MODE 0: iter1 uniform c. MODE 1: iter2 (b_old=0, writes bl). MODE 2: iter3.
//
// grid = 4*NCH, remapped for XCD locality: xcd = bid&7, q = bid>>3;
//   ch = (q>>2)*8 + xcd  (i-chunk of CI),  bq = q&3  (b-quarter, 16 b's).
//
// Pipeline (R5 fix): stage(i+1) is issued AFTER the top-of-iteration
// __syncthreads(), so the barrier's implicit vmcnt(0) only drains the stage
// issued a full iteration earlier (latency hidden under compute), instead of
// draining the just-issued prefetch every iteration.
//
// W[i] (16KB) staged per-i into LDS via global_load_lds, double-buffered,
// with XOR-swizzled SOURCE so the per-thread ds_read_b128 of 8 contiguous
// float4s is bank-conflict-minimal:
//   LDS f4 slot p holds W f4  src(p) = (p&~7) | ((p&7) ^ ((p>>3)&7))
//   thread reads wr[r] at LDS f4 slot*8 + (r ^ (slot&7))  == W f4 slot*8+r.
// ---------------------------------------------------------------------------
template<int MODE, int NCH>
__global__ __launch_bounds__(256) void fusedK(
    const float* __restrict__ x, const float* __restrict__ W,
    const float* __restrict__ v, const float* __restrict__ blin,
    float* __restrict__ blout, float* __restrict__ part,
    float* __restrict__ zpart)
{
  constexpr int CI = IC / NCH;
  const int t    = threadIdx.x;
  const int xcd  = blockIdx.x & 7;
  const int q    = blockIdx.x >> 3;
  const int ch   = (q >> 2) * 8 + xcd;
  const int bq   = q & 3;
  const int slot = t & 127;
  const int bg   = t >> 7;
  const int o    = slot >> 2;
  const int dq   = slot & 3;
  const int lane = t & 63;
  const int w    = t >> 6;
  const int i0   = ch * CI;
  const int bqb  = bq * 16;            // block's first b
  const int s7   = slot & 7;
  const int sbase = slot * 8;          // f4 base of this thread's W slice

  __shared__ float Wbuf[2][4096];                         // 2 x 16 KB
  __shared__ float xbuf[2][128];                          // 2 x 512 B
  __shared__ float blbuf[(MODE == 2) ? 2 : 1][(MODE == 2) ? 512 : 4];

  const float4* Wg  = (const float4*)W;
  const float4* xg  = (const float4*)x;
  const float4* blg = (const float4*)blin;

  float4 accv[8];
  float  zacc[8];
  float4 vreg[8];
#pragma unroll
  for (int bb = 0; bb < 8; ++bb) { accv[bb] = make_float4(0,0,0,0); zacc[bb] = 0.f; }

  if constexpr (MODE != 0) {
#pragma unroll
    for (int bb = 0; bb < 8; ++bb) {
      const int b = bqb + bg * 8 + bb;
      vreg[bb] = *(const float4*)(v + ((size_t)b * 32 + o) * 16 + dq * 4);
    }
  }

  auto stage = [&](int i, int nb) {
    // W[i]: 4 gload rounds per wave, swizzled source, linear LDS dest
    const float4* Wi = Wg + (size_t)i * 1024;
#pragma unroll
    for (int k = 0; k < 4; ++k) {
      const int p   = w * 256 + k * 64 + lane;
      const int src = (p & ~7) | ((p & 7) ^ ((p >> 3) & 7));
      GLOAD_LDS16(Wi + src, &Wbuf[nb][(w * 256 + k * 64) * 4]);
    }
    // x[bqb..bqb+16, i, 0..8): 32 f4, wave 0 lanes 0..31, linear dest
    if (t < 32) {
      GLOAD_LDS16(xg + (size_t)(bqb + (t >> 1)) * 4096 + i * 2 + (t & 1),
                  &xbuf[nb][0]);
    }
    // bl[i, bqb..bqb+16, 0..32): 128 f4, waves 0-1, linear dest
    if constexpr (MODE == 2) {
      if (t < 128) {
        GLOAD_LDS16(blg + (size_t)i * 512 + bq * 128 + t,
                    &blbuf[nb][(t >> 6) * 256]);
      }
    }
  };

  stage(i0, 0);

  for (int ii = 0; ii < CI; ++ii) {
    const int cur = ii & 1;
    const int i   = i0 + ii;

    // Drain stage(i) (issued a full iteration ago) and protect buffer reuse.
    __syncthreads();
    // Prefetch i+1; stays in flight across this iteration's compute.
    if (ii + 1 < CI) stage(i + 1, cur ^ 1);

    // W fragment from LDS (swizzled addresses; wr[r] == W f4 slot*8+r)
    const float* Wb = &Wbuf[cur][0];
    float4 wr[8];
#pragma unroll
    for (int r = 0; r < 8; ++r)
      wr[r] = *(const float4*)&Wb[(sbase + (r ^ s7)) * 4];

#pragma unroll
    for (int bb = 0; bb < 8; ++bb) {
      const int bl_loc = bg * 8 + bb;                    // b-local in [0,16)
      const float4 xa = *(const float4*)&xbuf[cur][bl_loc * 8];
      const float4 xc = *(const float4*)&xbuf[cur][bl_loc * 8 + 4];
      float4 u;
      u.x = dot8(wr[0], wr[1], xa, xc);
      u.y = dot8(wr[2], wr[3], xa, xc);
      u.z = dot8(wr[4], wr[5], xa, xc);
      u.w = dot8(wr[6], wr[7], xa, xc);
      if constexpr (MODE == 0) {
        accv[bb].x += u.x; accv[bb].y += u.y;
        accv[bb].z += u.z; accv[bb].w += u.w;
      } else {
        const float4 vv = vreg[bb];
        float pd = u.x * vv.x + u.y * vv.y + u.z * vv.z + u.w * vv.w;
        pd += __shfl_xor(pd, 1);             // reduce over dq (lane bits 0-1)
        pd += __shfl_xor(pd, 2);
        float bnew = pd;
        if constexpr (MODE == 2) bnew += blbuf[cur][bl_loc * 32 + o];
        if constexpr (MODE == 1) {
          if (dq == 0)
            blout[(size_t)i * 2048 + (size_t)(bqb + bl_loc) * 32 + o] = bnew;
        }
        const float p = __expf(bnew);
        accv[bb].x = fmaf(p, u.x, accv[bb].x);
        accv[bb].y = fmaf(p, u.y, accv[bb].y);
        accv[bb].z = fmaf(p, u.z, accv[bb].z);
        accv[bb].w = fmaf(p, u.w, accv[bb].w);
        zacc[bb] += p;
      }
    }
  }

  // epilogue: part[ch][b][o][d] as f4 at dq; zpart[ch][b*32+o]
  float4* part4 = (float4*)part;
#pragma unroll
  for (int bb = 0; bb < 8; ++bb) {
    const int b = bqb + bg * 8 + bb;
    part4[((size_t)ch * 64 + b) * 128 + o * 4 + dq] = accv[bb];
    if constexpr (MODE != 0) {
      if (dq == 0) zpart[(size_t)ch * 2048 + b * 32 + o] = zacc[bb];
    }
  }
}

// ---------------------------------------------------------------------------
// Reduce s partials over chunks, normalize by Z (or uniform scale), squash.
// grid 128 x 256; one thread per (b,o,d); g = b*512 + o*16 + d.
// ---------------------------------------------------------------------------
template<bool WITH_Z, int NCH>
__global__ __launch_bounds__(256) void reduceSquash(
    const float* __restrict__ part, const float* __restrict__ rz,
    float* __restrict__ vout, float scale)
{
  const int g = blockIdx.x * 256 + threadIdx.x;
  float s = 0.f;
#pragma unroll 8
  for (int ch = 0; ch < NCH; ++ch) s += part[(size_t)ch * 32768 + g];
  if constexpr (WITH_Z) s *= rz[g >> 4];
  else                  s *= scale;

  float sq = s * s;
#pragma unroll
  for (int k = 1; k < 16; k <<= 1) sq += __shfl_xor(sq, k);   // sum over d
  const float f = (sq / (1.f + sq)) * rsqrtf(sq + 1e-9f);
  vout[g] = s * f;
}

// ---------------------------------------------------------------------------
// Z reduction: rz[b*32+o] = 1 / sum_ch zpart[ch][...]. grid 8 x 256.
// ---------------------------------------------------------------------------
template<int NCH>
__global__ __launch_bounds__(256) void zredK(
    const float* __restrict__ zpart, float* __restrict__ rz)
{
  const int j = blockIdx.x * 256 + threadIdx.x;
  float zs = 0.f;
#pragma unroll 8
  for (int ch = 0; ch < NCH; ++ch) zs += zpart[(size_t)ch * 2048 + j];
  rz[j] = 1.f / zs;
}

// ---------------------------------------------------------------------------
extern "C" void kernel_launch(void* const* d_in, const int* in_sizes, int n_in,
                              void* d_out, int out_size, void* d_ws, size_t ws_size,
                              hipStream_t stream) {
  (void)in_sizes; (void)n_in; (void)out_size;
  const float* x = (const float*)d_in[0];
  const float* W = (const float*)d_in[1];
  float* out = (float*)d_out;
  float* ws  = (float*)d_ws;

  auto run = [&](auto tag) {
    constexpr int NCH = decltype(tag)::value;
    float* bl    = ws;                                 // [2048][64][32]
    float* part  = bl + (size_t)IC * B_ * OC;          // [NCH][64][32][16]
    float* zpart = part + (size_t)NCH * 32768;         // [NCH][2048]
    float* rz    = zpart + (size_t)NCH * 2048;         // [2048]
    float* v     = rz + 2048;                          // [64][32][16]

    const dim3 gF(4 * NCH), b256(256);
    // iter 1: uniform c = 1/2048
    fusedK<0, NCH><<<gF, b256, 0, stream>>>(x, W, nullptr, nullptr, nullptr, part, nullptr);
    reduceSquash<false, NCH><<<dim3(128), b256, 0, stream>>>(part, nullptr, v, 1.f / 2048.f);
    // iter 2: b1 = u.v1 (written to bl), s2 = sum exp(b1) u / Z
    fusedK<1, NCH><<<gF, b256, 0, stream>>>(x, W, v, nullptr, bl, part, zpart);
    zredK<NCH><<<dim3(8), b256, 0, stream>>>(zpart, rz);
    reduceSquash<true, NCH><<<dim3(128), b256, 0, stream>>>(part, rz, v, 0.f);
    // iter 3: b2 = b1 + u.v2, s3, final v -> out
    fusedK<2, NCH><<<gF, b256, 0, stream>>>(x, W, v, bl, nullptr, part, zpart);
    zredK<NCH><<<dim3(8), b256, 0, stream>>>(zpart, rz);
    reduceSquash<true, NCH><<<dim3(128), b256, 0, stream>>>(part, rz, out, 0.f);
  };

  const size_t need256 =
      ((size_t)IC * B_ * OC + 256ul * 32768 + 256ul * 2048 + 2048 + 32768) * 4;
  if (ws_size >= need256) run(std::integral_constant<int, 256>{});
  else                    run(std::integral_constant<int, 64>{});
}

// Round 6
// 171.468 us; speedup vs baseline: 1.8948x; 1.0641x over previous
//
#include <hip/hip_runtime.h>
#include <math.h>

#define B_ 64
#define IC 2048
#define OC 32
#define OD 16
#define ID 8

#define GLOAD_LDS16(gp, lp)                                                       \
  __builtin_amdgcn_global_load_lds((const __attribute__((address_space(1))) void*)(gp), \
                                   (__attribute__((address_space(3))) void*)(lp), \
                                   16, 0, 0)

__device__ __forceinline__ float dot8(const float4 w0, const float4 w1,
                                      const float4 xa, const float4 xb) {
  return w0.x*xa.x + w0.y*xa.y + w0.z*xa.z + w0.w*xa.w
       + w1.x*xb.x + w1.y*xb.y + w1.z*xb.z + w1.w*xb.w;
}

// ---------------------------------------------------------------------------
// Fused routing kernel (recompute u_hat; b-logit update + unnormalized
// exp-weighted s accumulation; Z applied later in reduceSquash).
// MODE 0: iter1 uniform c. MODE 1: iter2 (b_old=0, writes bl). MODE 2: iter3.
//
// grid = 4*NCH, remapped for XCD locality: xcd = bid&7, q = bid>>3;
//   ch = (q>>2)*8 + xcd  (i-chunk of CI),  bq = q&3  (b-quarter, 16 b's).
//
// R6 structure:
//  - i-loop is #pragma unroll 1 (body ~450 insts, fits L1I; R4/R5's full
//    unroll was ~28KB of streaming code = L1I thrash suspect).
//  - x and bl are staged ONCE per 8-i subwindow (single-buffered LDS);
//    per-iteration staging is W only (4 gload_lds/wave, double-buffered,
//    XOR-swizzled source so ds_read_b128 of 8 f4/thread is conflict-min).
//  - LDS 52KB (MODE2) -> 3 blocks/CU, matching the VGPR-136 limit.
// ---------------------------------------------------------------------------
template<int MODE, int NCH>
__global__ __launch_bounds__(256) void fusedK(
    const float* __restrict__ x, const float* __restrict__ W,
    const float* __restrict__ v, const float* __restrict__ blin,
    float* __restrict__ blout, float* __restrict__ part,
    float* __restrict__ zpart)
{
  constexpr int CI  = IC / NCH;
  constexpr int NSW = CI / 8;          // 8-i subwindows
  const int t    = threadIdx.x;
  const int xcd  = blockIdx.x & 7;
  const int q    = blockIdx.x >> 3;
  const int ch   = (q >> 2) * 8 + xcd;
  const int bq   = q & 3;
  const int slot = t & 127;
  const int bg   = t >> 7;
  const int o    = slot >> 2;
  const int dq   = slot & 3;
  const int lane = t & 63;
  const int w    = t >> 6;
  const int i0   = ch * CI;
  const int bqb  = bq * 16;            // block's first b
  const int s7   = slot & 7;
  const int sbase = slot * 8;          // f4 base of this thread's W slice

  __shared__ float Wbuf[2][4096];                          // 2 x 16 KB
  __shared__ float xall[16 * 64];                          // [b16][i8*2+half] f4 -> 4 KB
  __shared__ float blall[(MODE == 2) ? 4096 : 4];          // [i8][b16*32] -> 16 KB

  const float4* Wg  = (const float4*)W;
  const float4* xg  = (const float4*)x;
  const float4* blg = (const float4*)blin;

  float4 accv[8];
  float  zacc[8];
  float4 vreg[8];
#pragma unroll
  for (int bb = 0; bb < 8; ++bb) { accv[bb] = make_float4(0,0,0,0); zacc[bb] = 0.f; }

  if constexpr (MODE != 0) {
#pragma unroll
    for (int bb = 0; bb < 8; ++bb) {
      const int b = bqb + bg * 8 + bb;
      vreg[bb] = *(const float4*)(v + ((size_t)b * 32 + o) * 16 + dq * 4);
    }
  }

  auto stageW = [&](int i, int nb) {
    const float4* Wi = Wg + (size_t)i * 1024;
#pragma unroll
    for (int k = 0; k < 4; ++k) {
      const int p   = w * 256 + k * 64 + lane;
      const int src = (p & ~7) | ((p & 7) ^ ((p >> 3) & 7));
      GLOAD_LDS16(Wi + src, &Wbuf[nb][(w * 256 + k * 64) * 4]);
    }
  };

  auto stageXBL = [&](int sw) {
    // x window: 16 b x 8 i -> 256 f4; xall[bb][r] f4, linear
    {
      const int fidx = w * 64 + lane;
      const int bb = fidx >> 4, r = fidx & 15;
      GLOAD_LDS16(xg + (size_t)(bqb + bb) * 4096 + (i0 + sw * 8) * 2 + r,
                  &xall[(w * 64) * 4]);
    }
    // bl window: 8 i x 128 f4 -> 1024 f4; blall[ii][r] f4, linear
    if constexpr (MODE == 2) {
#pragma unroll
      for (int k = 0; k < 4; ++k) {
        const int fidx = k * 256 + w * 64 + lane;
        const int ii = fidx >> 7, r = fidx & 127;
        GLOAD_LDS16(blg + (size_t)(i0 + sw * 8 + ii) * 512 + bq * 128 + r,
                    &blall[(k * 256 + w * 64) * 4]);
      }
    }
  };

  stageXBL(0);
  stageW(i0, 0);
  int cur = 0;

#pragma unroll 1
  for (int sw = 0; sw < NSW; ++sw) {
#pragma unroll 1
    for (int j = 0; j < 8; ++j) {
      const int ii = sw * 8 + j;
      const int i  = i0 + ii;

      __syncthreads();                      // drains stage(ii) (+x/bl at window start)
      if (ii + 1 < CI) stageW(i + 1, cur ^ 1);   // in flight across this compute

      const float* Wb = &Wbuf[cur][0];
      float4 wr[8];
#pragma unroll
      for (int r = 0; r < 8; ++r)
        wr[r] = *(const float4*)&Wb[(sbase + (r ^ s7)) * 4];

#pragma unroll
      for (int bb = 0; bb < 8; ++bb) {
        const int bl_loc = bg * 8 + bb;                    // b-local in [0,16)
        const float4 xa = *(const float4*)&xall[bl_loc * 64 + j * 8];
        const float4 xc = *(const float4*)&xall[bl_loc * 64 + j * 8 + 4];
        float4 u;
        u.x = dot8(wr[0], wr[1], xa, xc);
        u.y = dot8(wr[2], wr[3], xa, xc);
        u.z = dot8(wr[4], wr[5], xa, xc);
        u.w = dot8(wr[6], wr[7], xa, xc);
        if constexpr (MODE == 0) {
          accv[bb].x += u.x; accv[bb].y += u.y;
          accv[bb].z += u.z; accv[bb].w += u.w;
        } else {
          const float4 vv = vreg[bb];
          float pd = u.x * vv.x + u.y * vv.y + u.z * vv.z + u.w * vv.w;
          pd += __shfl_xor(pd, 1);             // reduce over dq (lane bits 0-1)
          pd += __shfl_xor(pd, 2);
          float bnew = pd;
          if constexpr (MODE == 2) bnew += blall[j * 512 + bl_loc * 32 + o];
          if constexpr (MODE == 1) {
            if (dq == 0)
              blout[(size_t)i * 2048 + (size_t)(bqb + bl_loc) * 32 + o] = bnew;
          }
          const float p = __expf(bnew);
          accv[bb].x = fmaf(p, u.x, accv[bb].x);
          accv[bb].y = fmaf(p, u.y, accv[bb].y);
          accv[bb].z = fmaf(p, u.z, accv[bb].z);
          accv[bb].w = fmaf(p, u.w, accv[bb].w);
          zacc[bb] += p;
        }
      }
      cur ^= 1;
    }
    if (sw + 1 < NSW) {
      __syncthreads();            // all waves done with xall/blall window
      stageXBL(sw + 1);           // drained by next top-of-iteration barrier
    }
  }

  // epilogue: part[ch][b][o][d] as f4 at dq; zpart[ch][b*32+o]
  float4* part4 = (float4*)part;
#pragma unroll
  for (int bb = 0; bb < 8; ++bb) {
    const int b = bqb + bg * 8 + bb;
    part4[((size_t)ch * 64 + b) * 128 + o * 4 + dq] = accv[bb];
    if constexpr (MODE != 0) {
      if (dq == 0) zpart[(size_t)ch * 2048 + b * 32 + o] = zacc[bb];
    }
  }
}

// ---------------------------------------------------------------------------
// Reduce s partials over chunks, normalize by Z (or uniform scale), squash.
// grid 128 x 256; one thread per (b,o,d); g = b*512 + o*16 + d.
// ---------------------------------------------------------------------------
template<bool WITH_Z, int NCH>
__global__ __launch_bounds__(256) void reduceSquash(
    const float* __restrict__ part, const float* __restrict__ rz,
    float* __restrict__ vout, float scale)
{
  const int g = blockIdx.x * 256 + threadIdx.x;
  float s = 0.f;
#pragma unroll 8
  for (int ch = 0; ch < NCH; ++ch) s += part[(size_t)ch * 32768 + g];
  if constexpr (WITH_Z) s *= rz[g >> 4];
  else                  s *= scale;

  float sq = s * s;
#pragma unroll
  for (int k = 1; k < 16; k <<= 1) sq += __shfl_xor(sq, k);   // sum over d
  const float f = (sq / (1.f + sq)) * rsqrtf(sq + 1e-9f);
  vout[g] = s * f;
}

// ---------------------------------------------------------------------------
// Z reduction: rz[b*32+o] = 1 / sum_ch zpart[ch][...]. grid 8 x 256.
// ---------------------------------------------------------------------------
template<int NCH>
__global__ __launch_bounds__(256) void zredK(
    const float* __restrict__ zpart, float* __restrict__ rz)
{
  const int j = blockIdx.x * 256 + threadIdx.x;
  float zs = 0.f;
#pragma unroll 8
  for (int ch = 0; ch < NCH; ++ch) zs += zpart[(size_t)ch * 2048 + j];
  rz[j] = 1.f / zs;
}

// ---------------------------------------------------------------------------
extern "C" void kernel_launch(void* const* d_in, const int* in_sizes, int n_in,
                              void* d_out, int out_size, void* d_ws, size_t ws_size,
                              hipStream_t stream) {
  (void)in_sizes; (void)n_in; (void)out_size;
  const float* x = (const float*)d_in[0];
  const float* W = (const float*)d_in[1];
  float* out = (float*)d_out;
  float* ws  = (float*)d_ws;

  auto run = [&](auto tag) {
    constexpr int NCH = decltype(tag)::value;
    float* bl    = ws;                                 // [2048][64][32]
    float* part  = bl + (size_t)IC * B_ * OC;          // [NCH][64][32][16]
    float* zpart = part + (size_t)NCH * 32768;         // [NCH][2048]
    float* rz    = zpart + (size_t)NCH * 2048;         // [2048]
    float* v     = rz + 2048;                          // [64][32][16]

    const dim3 gF(4 * NCH), b256(256);
    // iter 1: uniform c = 1/2048
    fusedK<0, NCH><<<gF, b256, 0, stream>>>(x, W, nullptr, nullptr, nullptr, part, nullptr);
    reduceSquash<false, NCH><<<dim3(128), b256, 0, stream>>>(part, nullptr, v, 1.f / 2048.f);
    // iter 2: b1 = u.v1 (written to bl), s2 = sum exp(b1) u / Z
    fusedK<1, NCH><<<gF, b256, 0, stream>>>(x, W, v, nullptr, bl, part, zpart);
    zredK<NCH><<<dim3(8), b256, 0, stream>>>(zpart, rz);
    reduceSquash<true, NCH><<<dim3(128), b256, 0, stream>>>(part, rz, v, 0.f);
    // iter 3: b2 = b1 + u.v2, s3, final v -> out
    fusedK<2, NCH><<<gF, b256, 0, stream>>>(x, W, v, bl, nullptr, part, zpart);
    zredK<NCH><<<dim3(8), b256, 0, stream>>>(zpart, rz);
    reduceSquash<true, NCH><<<dim3(128), b256, 0, stream>>>(part, rz, out, 0.f);
  };

  const size_t need256 =
      ((size_t)IC * B_ * OC + 256ul * 32768 + 256ul * 2048 + 2048 + 32768) * 4;
  if (ws_size >= need256) run(std::integral_constant<int, 256>{});
  else                    run(std::integral_constant<int, 64>{});
}

// Round 7
// 159.491 us; speedup vs baseline: 2.0371x; 1.0751x over previous
//
#include <hip/hip_runtime.h>
#include <math.h>

#define B_ 64
#define IC 2048
#define OC 32
#define OD 16
#define ID 8

#define GLOAD_LDS16(gp, lp)                                                       \
  __builtin_amdgcn_global_load_lds((const __attribute__((address_space(1))) void*)(gp), \
                                   (__attribute__((address_space(3))) void*)(lp), \
                                   16, 0, 0)

__device__ __forceinline__ float dot8(const float4 w0, const float4 w1,
                                      const float4 xa, const float4 xb) {
  return w0.x*xa.x + w0.y*xa.y + w0.z*xa.z + w0.w*xa.w
       + w1.x*xb.x + w1.y*xb.y + w1.z*xb.z + w1.w*xb.w;
}

// ---------------------------------------------------------------------------
// Fused routing pass. Key algebra (R7): u_hat is iteration-invariant, so the
// b-logit after iter k is b_k = u . (v1 + ... + vk). No bl buffer exists;
// the kernel takes vs = running sum of v's and computes p = exp(u.vs) on the
// fly, accumulating s_part = sum_i p*u and Z_part = sum_i p (normalization
// applied later in reduceSquash, by linearity).
//
// Geometry: grid = 4(bh) x NCH, XCD-remapped: xcd=bid&7, q=bid>>3,
//   ch = (q>>2)*8+xcd (i-chunk of CI), bh = q&3.
// Block 256 = 4 waves; wave wv owns b = bh*16 + wv*4 + bb (4 b's, uniform ->
// x loads are wave-uniform scalar loads, no LDS). Lane: op=lane>>2 ->
// o in {op,op+16}; dq=lane&3 -> d in [dq*4,dq*4+4).
// Register tile per thread: 2 o x 4 d x 4 b; 256 FMA vs 16 ds_read_b128/i.
//
// W[i] (16KB) staged per-i via global_load_lds, double-buffered, source
// XOR-swizzled (involution src(p)=(p&~7)|((p&7)^((p>>3)&7))) so the
// per-thread read of 8 contiguous f4 is spread across banks.
// ---------------------------------------------------------------------------
template<bool WEIGHTED, int NCH>
__global__ __launch_bounds__(256) void fusedK(
    const float* __restrict__ x, const float* __restrict__ W,
    const float* __restrict__ vs, float* __restrict__ part,
    float* __restrict__ zpart)
{
  constexpr int CI = IC / NCH;
  const int t    = threadIdx.x;
  const int xcd  = blockIdx.x & 7;
  const int q    = blockIdx.x >> 3;
  const int ch   = (q >> 2) * 8 + xcd;
  const int bh   = q & 3;
  const int lane = t & 63;
  const int wv   = t >> 6;
  const int wu   = __builtin_amdgcn_readfirstlane(wv);   // wave-uniform wave id
  const int op   = lane >> 2;
  const int dq   = lane & 3;
  const int rot  = lane & 7;
  const int i0   = ch * CI;
  const int b0   = bh * 16 + wu * 4;     // wave's first b (SGPR)

  __shared__ float Wbuf[2][4096];        // 2 x 16 KB (1024 f4 each)

  const float4* Wg = (const float4*)W;

  float4 acc[8];                         // [o2][bb]
  float  zacc[8];
  float4 vreg[8];
#pragma unroll
  for (int k = 0; k < 8; ++k) { acc[k] = make_float4(0,0,0,0); zacc[k] = 0.f; }

  if constexpr (WEIGHTED) {
#pragma unroll
    for (int o2 = 0; o2 < 2; ++o2)
#pragma unroll
      for (int bb = 0; bb < 4; ++bb)
        vreg[o2 * 4 + bb] = *(const float4*)(
            vs + ((size_t)(b0 + bb) * 32 + op + o2 * 16) * 16 + dq * 4);
  }

  auto stageW = [&](int i, int nb) {
    const float4* Wi = Wg + (size_t)i * 1024;
#pragma unroll
    for (int k = 0; k < 4; ++k) {
      const int p   = wv * 256 + k * 64 + lane;
      const int src = (p & ~7) | ((p & 7) ^ ((p >> 3) & 7));
      GLOAD_LDS16(Wi + src, &Wbuf[nb][(wv * 256 + k * 64) * 4]);
    }
  };

  stageW(i0, 0);

#pragma unroll 1
  for (int ii = 0; ii < CI; ++ii) {
    const int cur = ii & 1;
    const int i   = i0 + ii;

    __syncthreads();                       // drains stage(ii) issued last iter
    if (ii + 1 < CI) stageW(i + 1, cur ^ 1);

    // x[b0..b0+4][i][0..8): wave-uniform -> scalar loads
    const float* xb = x + ((size_t)b0 * IC + i) * ID;
    float4 xa[4], xc[4];
#pragma unroll
    for (int bb = 0; bb < 4; ++bb) {
      const float* p = xb + (size_t)bb * (IC * ID);
      xa[bb] = *(const float4*)p;
      xc[bb] = *(const float4*)(p + 4);
    }

    const float* Wb = &Wbuf[cur][0];
#pragma unroll
    for (int o2 = 0; o2 < 2; ++o2) {
      const int jb = (op + o2 * 16) * 32 + dq * 8;   // thread's W f4 base
      float4 wr[8];
#pragma unroll
      for (int r = 0; r < 8; ++r)
        wr[r] = *(const float4*)&Wb[(jb + (r ^ rot)) * 4];

#pragma unroll
      for (int bb = 0; bb < 4; ++bb) {
        float4 u;
        u.x = dot8(wr[0], wr[1], xa[bb], xc[bb]);
        u.y = dot8(wr[2], wr[3], xa[bb], xc[bb]);
        u.z = dot8(wr[4], wr[5], xa[bb], xc[bb]);
        u.w = dot8(wr[6], wr[7], xa[bb], xc[bb]);
        const int k = o2 * 4 + bb;
        if constexpr (!WEIGHTED) {
          acc[k].x += u.x; acc[k].y += u.y; acc[k].z += u.z; acc[k].w += u.w;
        } else {
          const float4 vv = vreg[k];
          float pd = u.x * vv.x + u.y * vv.y + u.z * vv.z + u.w * vv.w;
          pd += __shfl_xor(pd, 1);           // reduce over dq (lane bits 0-1)
          pd += __shfl_xor(pd, 2);
          const float p = __expf(pd);        // p = exp(u . vs), unnormalized c
          acc[k].x = fmaf(p, u.x, acc[k].x);
          acc[k].y = fmaf(p, u.y, acc[k].y);
          acc[k].z = fmaf(p, u.z, acc[k].z);
          acc[k].w = fmaf(p, u.w, acc[k].w);
          zacc[k] += p;
        }
      }
    }
  }

  // epilogue: part[ch][b][o][d] as f4; zpart[ch][b*32+o] (dq==0 lanes)
  float4* part4 = (float4*)part;
#pragma unroll
  for (int o2 = 0; o2 < 2; ++o2)
#pragma unroll
    for (int bb = 0; bb < 4; ++bb) {
      const int b = b0 + bb;
      const int o = op + o2 * 16;
      part4[((size_t)ch * 64 + b) * 128 + o * 4 + dq] = acc[o2 * 4 + bb];
      if constexpr (WEIGHTED) {
        if (dq == 0) zpart[(size_t)ch * 2048 + b * 32 + o] = zacc[o2 * 4 + bb];
      }
    }
}

// ---------------------------------------------------------------------------
// Reduce s partials over chunks, normalize, squash.
// PASS 0: s*=1/2048, vs[g]  = v   (v1; also the running sum)
// PASS 1: s*=rz,     vs[g] += v   (vs = v1+v2)
// PASS 2: s*=rz,     out[g] = v   (final)
// grid 128 x 256; g = b*512 + o*16 + d.
// ---------------------------------------------------------------------------
template<int PASS, int NCH>
__global__ __launch_bounds__(256) void reduceSquash(
    const float* __restrict__ part, const float* __restrict__ rz,
    float* __restrict__ vsio, float* __restrict__ out)
{
  const int g = blockIdx.x * 256 + threadIdx.x;
  float s = 0.f;
#pragma unroll 8
  for (int ch = 0; ch < NCH; ++ch) s += part[(size_t)ch * 32768 + g];
  if constexpr (PASS == 0) s *= (1.f / 2048.f);
  else                     s *= rz[g >> 4];

  float sq = s * s;
#pragma unroll
  for (int k = 1; k < 16; k <<= 1) sq += __shfl_xor(sq, k);   // sum over d
  const float f = (sq / (1.f + sq)) * rsqrtf(sq + 1e-9f);
  const float v = s * f;

  if constexpr (PASS == 0)      vsio[g] = v;
  else if constexpr (PASS == 1) vsio[g] += v;
  else                          out[g] = v;
}

// ---------------------------------------------------------------------------
// Z reduction: rz[b*32+o] = 1 / sum_ch zpart. grid 8 x 256.
// ---------------------------------------------------------------------------
template<int NCH>
__global__ __launch_bounds__(256) void zredK(
    const float* __restrict__ zpart, float* __restrict__ rz)
{
  const int j = blockIdx.x * 256 + threadIdx.x;
  float zs = 0.f;
#pragma unroll 8
  for (int ch = 0; ch < NCH; ++ch) zs += zpart[(size_t)ch * 2048 + j];
  rz[j] = 1.f / zs;
}

// ---------------------------------------------------------------------------
extern "C" void kernel_launch(void* const* d_in, const int* in_sizes, int n_in,
                              void* d_out, int out_size, void* d_ws, size_t ws_size,
                              hipStream_t stream) {
  (void)in_sizes; (void)n_in; (void)out_size;
  const float* x = (const float*)d_in[0];
  const float* W = (const float*)d_in[1];
  float* out = (float*)d_out;
  float* ws  = (float*)d_ws;

  auto run = [&](auto tag) {
    constexpr int NCH = decltype(tag)::value;
    float* part  = ws;                                 // [NCH][64][32][16]
    float* zpart = part + (size_t)NCH * 32768;         // [NCH][2048]
    float* rz    = zpart + (size_t)NCH * 2048;         // [2048]
    float* vsb   = rz + 2048;                          // vs running sum [32768]

    const dim3 gF(4 * NCH), b256(256), gR(128);
    // pass 1: uniform c -> v1 (vs = v1)
    fusedK<false, NCH><<<gF, b256, 0, stream>>>(x, W, nullptr, part, nullptr);
    reduceSquash<0, NCH><<<gR, b256, 0, stream>>>(part, nullptr, vsb, nullptr);
    // pass 2: p = exp(u.v1) -> v2; vs = v1+v2
    fusedK<true, NCH><<<gF, b256, 0, stream>>>(x, W, vsb, part, zpart);
    zredK<NCH><<<dim3(8), b256, 0, stream>>>(zpart, rz);
    reduceSquash<1, NCH><<<gR, b256, 0, stream>>>(part, rz, vsb, nullptr);
    // pass 3: p = exp(u.(v1+v2)) -> v3 = output
    fusedK<true, NCH><<<gF, b256, 0, stream>>>(x, W, vsb, part, zpart);
    zredK<NCH><<<dim3(8), b256, 0, stream>>>(zpart, rz);
    reduceSquash<2, NCH><<<gR, b256, 0, stream>>>(part, rz, nullptr, out);
  };

  const size_t need256 =
      ((size_t)256 * 32768 + 256ul * 2048 + 2048 + 32768) * 4;
  if (ws_size >= need256) run(std::integral_constant<int, 256>{});
  else                    run(std::integral_constant<int, 64>{});
}